// Round 3
// baseline (568.879 us; speedup 1.0000x reference)
//
#include <hip/hip_runtime.h>
#include <stdint.h>

#define IN_F 4096
#define OUT_F 4096
#define NROWS 8192

#define BM 256
#define BN 256
#define BK 64
#define NT (IN_F / BK)   // 64 K-tiles

typedef __attribute__((ext_vector_type(8))) short short8;
typedef __attribute__((ext_vector_type(4))) float floatx4;

static __device__ __forceinline__ unsigned short f2bf(float f) {
  union { float f; unsigned int u; } v; v.f = f;
  unsigned int u = v.u;
  return (unsigned short)((u + 0x7FFFu + ((u >> 16) & 1u)) >> 16);
}

static __device__ __forceinline__ void cr_coeffs(int o, int& j, float& c0, float& c1,
                                                 float& c2, float& c3) {
  float ts = ((float)o / 4095.0f) * 8.0f;
  j = (int)floorf(ts);
  j = j < 1 ? 1 : (j > 6 ? 6 : j);
  float t = ts - (float)j;
  float t2 = t * t, t3 = t2 * t;
  c0 = -0.5f * t3 + t2 - 0.5f * t;
  c1 = 1.5f * t3 - 2.5f * t2 + 1.0f;
  c2 = -1.5f * t3 + 2.0f * t2 + 0.5f * t;
  c3 = 0.5f * t3 - 0.5f * t2;
}

// ---- prepass 1: Wb = catmull_rom(cp) + residual, as bf16 ----
__global__ void build_w(const float* __restrict__ cp, const float* __restrict__ resid,
                        unsigned short* __restrict__ wb) {
  int idx = blockIdx.x * 256 + threadIdx.x;
  int o = idx >> 10;
  int g = idx & 1023;
  int j; float c0, c1, c2, c3;
  cr_coeffs(o, j, c0, c1, c2, c3);
  const float4* cpv = (const float4*)cp;
  int base = (j - 1) * 1024 + g;
  float4 p0 = cpv[base];
  float4 p1 = cpv[base + 1024];
  float4 p2 = cpv[base + 2048];
  float4 p3 = cpv[base + 3072];
  float4 r = ((const float4*)resid)[idx];
  float w0 = c0 * p0.x + c1 * p1.x + c2 * p2.x + c3 * p3.x + r.x;
  float w1 = c0 * p0.y + c1 * p1.y + c2 * p2.y + c3 * p3.y + r.y;
  float w2 = c0 * p0.z + c1 * p1.z + c2 * p2.z + c3 * p3.z + r.z;
  float w3 = c0 * p0.w + c1 * p1.w + c2 * p2.w + c3 * p3.w + r.w;
  union { unsigned short s[4]; uint2 u; } pk;
  pk.s[0] = f2bf(w0); pk.s[1] = f2bf(w1); pk.s[2] = f2bf(w2); pk.s[3] = f2bf(w3);
  ((uint2*)wb)[idx] = pk.u;
}

// ---- prepass 2: x fp32 -> bf16 ----
__global__ void convert_x(const float* __restrict__ x, unsigned short* __restrict__ xb) {
  int i = blockIdx.x * 256 + threadIdx.x;
  const float4* xv = (const float4*)x;
  float4 v0 = xv[2 * i], v1 = xv[2 * i + 1];
  union { unsigned short s[8]; uint4 u; } pk;
  pk.s[0] = f2bf(v0.x); pk.s[1] = f2bf(v0.y); pk.s[2] = f2bf(v0.z); pk.s[3] = f2bf(v0.w);
  pk.s[4] = f2bf(v1.x); pk.s[5] = f2bf(v1.y); pk.s[6] = f2bf(v1.z); pk.s[7] = f2bf(v1.w);
  ((uint4*)xb)[i] = pk.u;
}

#define MFMA_BF16(d, x, y) \
  d = __builtin_amdgcn_mfma_f32_16x16x32_bf16(x, y, d, 0, 0, 0)

// ---- main GEMM: 256x256 tile, BK=64, 8 waves, software-pipelined 8-phase ----
// Read-groups issued 1-2 phases before consumption so ds_read drains overlap
// other quadrants' MFMAs. One raw s_barrier per phase. Counted vmcnt(2) at
// P3/P7 only. LDS 16B-slot XOR swizzle both-sides (pre-swizzled global src
// for linear global_load_lds dest + swizzled ds_read).
__global__ __launch_bounds__(512, 2) void gemm_8p(
    const unsigned short* __restrict__ A,
    const unsigned short* __restrict__ B,
    const float* __restrict__ bias,
    float* __restrict__ C) {
  __shared__ unsigned short lds[2][2][BM * BK];   // 128 KiB

  const int tid = threadIdx.x;
  const int lane = tid & 63;
  const int wave = tid >> 6;   // 0..7
  const int wr = wave >> 2;    // M half
  const int wc = wave & 3;     // N quarter
  const int l15 = lane & 15;
  const int l4 = lane >> 4;

  const int bm = blockIdx.x >> 4;
  const int bn = blockIdx.x & 15;
  const size_t row0 = (size_t)bm * BM;
  const size_t col0 = (size_t)bn * BN;

  // stage 64 rows [r0,r0+64) of A(ab=0)/B(ab=1), K-tile kt -> buf (linear dest,
  // inverse-swizzled global source)
  auto stage = [&](int buf, int ab, int r0, const unsigned short* __restrict__ src,
                   size_t grow0, int kt) {
    const int rr = tid >> 3;
    const int sl = (tid & 7) ^ (rr & 7);
    const unsigned short* g = src + (grow0 + r0 + rr) * (size_t)IN_F + kt * BK + sl * 8;
    unsigned short* d = &lds[buf][ab][r0 * BK] + wave * 512;
    __builtin_amdgcn_global_load_lds(
        (const __attribute__((address_space(1))) void*)g,
        (__attribute__((address_space(3))) void*)d, 16, 0, 0);
  };
  auto ldA = [&](int buf, int aq, int m, int kk) -> short8 {
    const int r = wr * 128 + aq * 64 + m * 16 + l15;
    const int slot = (kk * 4 + l4) ^ (l15 & 7);   // r&7 == l15&7
    return *(const short8*)&lds[buf][0][r * BK + slot * 8];
  };
  auto ldB = [&](int buf, int j, int kk) -> short8 {
    const int r = wc * 64 + j * 16 + l15;
    const int slot = (kk * 4 + l4) ^ (l15 & 7);
    return *(const short8*)&lds[buf][1][r * BK + slot * 8];
  };

  floatx4 acc[8][4] = {};
  short8 aq0[4][2], aq1[4][2], b01x[2][2], b01y[2][2], b23[2][2];

  auto mmul = [&](int ar, int ac, short8 (&av)[4][2], short8 (&bv)[2][2]) {
    __builtin_amdgcn_s_setprio(1);
    #pragma unroll
    for (int m = 0; m < 4; ++m)
      #pragma unroll
      for (int n = 0; n < 2; ++n) {
        MFMA_BF16(acc[ar + m][ac + n], av[m][0], bv[n][0]);
        MFMA_BF16(acc[ar + m][ac + n], av[m][1], bv[n][1]);
      }
    __builtin_amdgcn_s_setprio(0);
  };

  // ---- prologue: kt0 full (8 issues) + kt1 A0A2,B2B3 (steady P7/P8 role) ----
  stage(0, 0, 0,   A, row0, 0); stage(0, 0, 64,  A, row0, 0);
  stage(0, 0, 128, A, row0, 0); stage(0, 0, 192, A, row0, 0);
  stage(0, 1, 0,   B, col0, 0); stage(0, 1, 64,  B, col0, 0);
  stage(0, 1, 128, B, col0, 0); stage(0, 1, 192, B, col0, 0);
  stage(1, 0, 0,   A, row0, 1); stage(1, 0, 128, A, row0, 1);
  stage(1, 1, 128, B, col0, 1); stage(1, 1, 192, B, col0, 1);
  asm volatile("s_waitcnt vmcnt(4)" ::: "memory");   // kt0's 8 landed
  __builtin_amdgcn_s_barrier();
  #pragma unroll
  for (int m = 0; m < 4; ++m) { aq0[m][0] = ldA(0, 0, m, 0); aq0[m][1] = ldA(0, 0, m, 1); }
  #pragma unroll
  for (int n = 0; n < 2; ++n) { b01x[n][0] = ldB(0, n, 0); b01x[n][1] = ldB(0, n, 1); }

  #pragma unroll 1
  for (int t = 0; t < NT / 2; ++t) {
    const int kt = 2 * t;
    const bool more = (t < NT / 2 - 1);

    // ---- P1: reads b23(kt), aq1(kt).0-1 [buf0]; stage kt+1 A1A3,B0B1 -> buf1
    b23[0][0] = ldB(0, 2, 0); b23[0][1] = ldB(0, 2, 1);
    b23[1][0] = ldB(0, 3, 0); b23[1][1] = ldB(0, 3, 1);
    aq1[0][0] = ldA(0, 1, 0, 0); aq1[0][1] = ldA(0, 1, 0, 1);
    aq1[1][0] = ldA(0, 1, 1, 0); aq1[1][1] = ldA(0, 1, 1, 1);
    stage(1, 0, 64, A, row0, kt + 1); stage(1, 0, 192, A, row0, kt + 1);
    stage(1, 1, 0,  B, col0, kt + 1); stage(1, 1, 64,  B, col0, kt + 1);
    __builtin_amdgcn_s_barrier();
    mmul(0, 0, aq0, b01x);                 // q0(kt) x b01(kt)

    // ---- P2: reads aq1(kt).2-3
    aq1[2][0] = ldA(0, 1, 2, 0); aq1[2][1] = ldA(0, 1, 2, 1);
    aq1[3][0] = ldA(0, 1, 3, 0); aq1[3][1] = ldA(0, 1, 3, 1);
    __builtin_amdgcn_s_barrier();
    mmul(0, 2, aq0, b23);                  // q0(kt) x b23(kt)

    // ---- P3: stage A0A2(kt+2)->buf0; vmcnt; post-barrier reads aq0(kt+1)[buf1]
    if (more) {
      stage(0, 0, 0, A, row0, kt + 2); stage(0, 0, 128, A, row0, kt + 2);
      asm volatile("s_waitcnt vmcnt(2)" ::: "memory");   // kt+1 fully landed
    } else {
      asm volatile("s_waitcnt vmcnt(0)" ::: "memory");
    }
    __builtin_amdgcn_s_barrier();
    #pragma unroll
    for (int m = 0; m < 4; ++m) { aq0[m][0] = ldA(1, 0, m, 0); aq0[m][1] = ldA(1, 0, m, 1); }
    mmul(4, 2, aq1, b23);                  // q1(kt) x b23(kt)

    // ---- P4: reads b01y = b01(kt+1)[buf1]; stage B2B3(kt+2)->buf0
    b01y[0][0] = ldB(1, 0, 0); b01y[0][1] = ldB(1, 0, 1);
    b01y[1][0] = ldB(1, 1, 0); b01y[1][1] = ldB(1, 1, 1);
    if (more) { stage(0, 1, 128, B, col0, kt + 2); stage(0, 1, 192, B, col0, kt + 2); }
    __builtin_amdgcn_s_barrier();
    mmul(4, 0, aq1, b01x);                 // q1(kt) x b01(kt)

    // ---- P5: reads b23(kt+1), aq1(kt+1).0-1 [buf1]; stage A1A3(kt+2)->buf0
    b23[0][0] = ldB(1, 2, 0); b23[0][1] = ldB(1, 2, 1);
    b23[1][0] = ldB(1, 3, 0); b23[1][1] = ldB(1, 3, 1);
    aq1[0][0] = ldA(1, 1, 0, 0); aq1[0][1] = ldA(1, 1, 0, 1);
    aq1[1][0] = ldA(1, 1, 1, 0); aq1[1][1] = ldA(1, 1, 1, 1);
    if (more) { stage(0, 0, 64, A, row0, kt + 2); stage(0, 0, 192, A, row0, kt + 2); }
    __builtin_amdgcn_s_barrier();
    mmul(0, 0, aq0, b01y);                 // q0(kt+1) x b01(kt+1)

    // ---- P6: reads aq1(kt+1).2-3; stage B0B1(kt+2)->buf0
    aq1[2][0] = ldA(1, 1, 2, 0); aq1[2][1] = ldA(1, 1, 2, 1);
    aq1[3][0] = ldA(1, 1, 3, 0); aq1[3][1] = ldA(1, 1, 3, 1);
    if (more) { stage(0, 1, 0, B, col0, kt + 2); stage(0, 1, 64, B, col0, kt + 2); }
    __builtin_amdgcn_s_barrier();
    mmul(0, 2, aq0, b23);                  // q0(kt+1) x b23(kt+1)

    // ---- P7: stage A0A2(kt+3)->buf1; vmcnt; post-barrier reads aq0(kt+2)[buf0]
    if (more) {
      stage(1, 0, 0, A, row0, kt + 3); stage(1, 0, 128, A, row0, kt + 3);
      asm volatile("s_waitcnt vmcnt(2)" ::: "memory");   // kt+2 fully landed
    }
    __builtin_amdgcn_s_barrier();
    if (more) {
      #pragma unroll
      for (int m = 0; m < 4; ++m) { aq0[m][0] = ldA(0, 0, m, 0); aq0[m][1] = ldA(0, 0, m, 1); }
    }
    mmul(4, 2, aq1, b23);                  // q1(kt+1) x b23(kt+1)

    // ---- P8: reads b01x = b01(kt+2)[buf0]; stage B2B3(kt+3)->buf1
    if (more) {
      b01x[0][0] = ldB(0, 0, 0); b01x[0][1] = ldB(0, 0, 1);
      b01x[1][0] = ldB(0, 1, 0); b01x[1][1] = ldB(0, 1, 1);
      stage(1, 1, 128, B, col0, kt + 3); stage(1, 1, 192, B, col0, kt + 3);
    }
    __builtin_amdgcn_s_barrier();
    mmul(4, 0, aq1, b01y);                 // q1(kt+1) x b01(kt+1)
  }

  // ---- epilogue: C = acc + bias.  D layout: row=(lane>>4)*4+r, col=lane&15
  #pragma unroll
  for (int n = 0; n < 4; ++n) {
    const size_t col = col0 + wc * 64 + n * 16 + l15;
    const float bv = bias[col];
    #pragma unroll
    for (int m = 0; m < 8; ++m) {
      const size_t rw = row0 + wr * 128 + m * 16 + l4 * 4;
      #pragma unroll
      for (int r = 0; r < 4; ++r)
        C[(rw + r) * OUT_F + col] = acc[m][n][r] + bv;
    }
  }
}

// ---- safety net: fp32 tiled GEMM w/ on-the-fly weight ----
__global__ void fallback_gemm(const float* __restrict__ x, const float* __restrict__ cp,
                              const float* __restrict__ resid, const float* __restrict__ bias,
                              float* __restrict__ out) {
  __shared__ float xs[64][32];
  __shared__ float ws[64][33];
  const int tid = threadIdx.x;
  const int bm = blockIdx.x / (OUT_F / 64);
  const int bn = blockIdx.x % (OUT_F / 64);
  const int row0 = bm * 64, col0 = bn * 64;
  const int tr = tid >> 4, tc = tid & 15;
  float acc[4][4] = {};
  for (int k0 = 0; k0 < IN_F; k0 += 32) {
    #pragma unroll
    for (int q = 0; q < 8; ++q) {
      int e = q * 256 + tid;
      int r = e >> 5, cc = e & 31;
      xs[r][cc] = x[(size_t)(row0 + r) * IN_F + k0 + cc];
      int o = col0 + r;
      int j; float c0, c1, c2, c3;
      cr_coeffs(o, j, c0, c1, c2, c3);
      size_t ci = (size_t)(j - 1) * IN_F + k0 + cc;
      ws[r][cc] = c0 * cp[ci] + c1 * cp[ci + IN_F] + c2 * cp[ci + 2 * IN_F] +
                  c3 * cp[ci + 3 * IN_F] + resid[(size_t)o * IN_F + k0 + cc];
    }
    __syncthreads();
    #pragma unroll
    for (int kk = 0; kk < 32; ++kk) {
      float xv[4], wv[4];
      #pragma unroll
      for (int i = 0; i < 4; ++i) xv[i] = xs[tr * 4 + i][kk];
      #pragma unroll
      for (int i = 0; i < 4; ++i) wv[i] = ws[tc * 4 + i][kk];
      #pragma unroll
      for (int i = 0; i < 4; ++i)
        #pragma unroll
        for (int jj = 0; jj < 4; ++jj) acc[i][jj] += xv[i] * wv[jj];
    }
    __syncthreads();
  }
  #pragma unroll
  for (int i = 0; i < 4; ++i)
    #pragma unroll
    for (int jj = 0; jj < 4; ++jj) {
      int row = row0 + tr * 4 + i, col = col0 + tc * 4 + jj;
      out[(size_t)row * OUT_F + col] = acc[i][jj] + bias[col];
    }
}

extern "C" void kernel_launch(void* const* d_in, const int* in_sizes, int n_in,
                              void* d_out, int out_size, void* d_ws, size_t ws_size,
                              hipStream_t stream) {
  const float* x = (const float*)d_in[0];
  const float* cp = (const float*)d_in[1];
  const float* resid = (const float*)d_in[2];
  const float* bias = (const float*)d_in[3];
  float* out = (float*)d_out;

  const size_t wb_bytes = (size_t)OUT_F * IN_F * 2;
  const size_t xb_bytes = (size_t)NROWS * IN_F * 2;

  if (ws_size >= wb_bytes + xb_bytes) {
    unsigned short* wb = (unsigned short*)d_ws;
    unsigned short* xb = (unsigned short*)((char*)d_ws + wb_bytes);
    hipLaunchKernelGGL(build_w, dim3(16384), dim3(256), 0, stream, cp, resid, wb);
    hipLaunchKernelGGL(convert_x, dim3(16384), dim3(256), 0, stream, x, xb);
    hipLaunchKernelGGL(gemm_8p, dim3(512), dim3(512), 0, stream, xb, wb, bias, out);
  } else {
    hipLaunchKernelGGL(fallback_gemm, dim3((NROWS / 64) * (OUT_F / 64)), dim3(256), 0,
                       stream, x, cp, resid, bias, out);
  }
}

// Round 4
// 289.055 us; speedup vs baseline: 1.9681x; 1.9681x over previous
//
#include <hip/hip_runtime.h>
#include <stdint.h>

#define IN_F 4096
#define OUT_F 4096
#define NROWS 8192

#define BM 256
#define BN 256
#define BK 64
#define NT (IN_F / BK)   // 64 K-tiles

typedef __attribute__((ext_vector_type(8))) short short8;
typedef __attribute__((ext_vector_type(4))) float floatx4;

static __device__ __forceinline__ unsigned short f2bf(float f) {
  union { float f; unsigned int u; } v; v.f = f;
  unsigned int u = v.u;
  return (unsigned short)((u + 0x7FFFu + ((u >> 16) & 1u)) >> 16);
}

static __device__ __forceinline__ void cr_coeffs(int o, int& j, float& c0, float& c1,
                                                 float& c2, float& c3) {
  float ts = ((float)o / 4095.0f) * 8.0f;
  j = (int)floorf(ts);
  j = j < 1 ? 1 : (j > 6 ? 6 : j);
  float t = ts - (float)j;
  float t2 = t * t, t3 = t2 * t;
  c0 = -0.5f * t3 + t2 - 0.5f * t;
  c1 = 1.5f * t3 - 2.5f * t2 + 1.0f;
  c2 = -1.5f * t3 + 2.0f * t2 + 0.5f * t;
  c3 = 0.5f * t3 - 0.5f * t2;
}

// ---- prepass 1: Wb = catmull_rom(cp) + residual, as bf16 ----
__global__ void build_w(const float* __restrict__ cp, const float* __restrict__ resid,
                        unsigned short* __restrict__ wb) {
  int idx = blockIdx.x * 256 + threadIdx.x;
  int o = idx >> 10;
  int g = idx & 1023;
  int j; float c0, c1, c2, c3;
  cr_coeffs(o, j, c0, c1, c2, c3);
  const float4* cpv = (const float4*)cp;
  int base = (j - 1) * 1024 + g;
  float4 p0 = cpv[base];
  float4 p1 = cpv[base + 1024];
  float4 p2 = cpv[base + 2048];
  float4 p3 = cpv[base + 3072];
  float4 r = ((const float4*)resid)[idx];
  float w0 = c0 * p0.x + c1 * p1.x + c2 * p2.x + c3 * p3.x + r.x;
  float w1 = c0 * p0.y + c1 * p1.y + c2 * p2.y + c3 * p3.y + r.y;
  float w2 = c0 * p0.z + c1 * p1.z + c2 * p2.z + c3 * p3.z + r.z;
  float w3 = c0 * p0.w + c1 * p1.w + c2 * p2.w + c3 * p3.w + r.w;
  union { unsigned short s[4]; uint2 u; } pk;
  pk.s[0] = f2bf(w0); pk.s[1] = f2bf(w1); pk.s[2] = f2bf(w2); pk.s[3] = f2bf(w3);
  ((uint2*)wb)[idx] = pk.u;
}

// ---- prepass 2: x fp32 -> bf16 ----
__global__ void convert_x(const float* __restrict__ x, unsigned short* __restrict__ xb) {
  int i = blockIdx.x * 256 + threadIdx.x;
  const float4* xv = (const float4*)x;
  float4 v0 = xv[2 * i], v1 = xv[2 * i + 1];
  union { unsigned short s[8]; uint4 u; } pk;
  pk.s[0] = f2bf(v0.x); pk.s[1] = f2bf(v0.y); pk.s[2] = f2bf(v0.z); pk.s[3] = f2bf(v0.w);
  pk.s[4] = f2bf(v1.x); pk.s[5] = f2bf(v1.y); pk.s[6] = f2bf(v1.z); pk.s[7] = f2bf(v1.w);
  ((uint4*)xb)[i] = pk.u;
}

#define MFMA_BF16(d, x, y) \
  d = __builtin_amdgcn_mfma_f32_16x16x32_bf16(x, y, d, 0, 0, 0)

// ---- main GEMM: 256x256 tile, BK=64, 8 waves, 8-phase, depth-2 prefetch ----
// Round-2 frag scheme (16 frags, fits 128 VGPR beside 128 acc), staging
// re-timed: tile T staged across P3(T-2),P4(T-2),P1(T-1),P2(T-1) -> every
// load has >=6 phases of slack; single vmcnt(4) per K-tile after P4 MFMA.
// Stage-write vs read-drain safety: A-region last read P3 (drained at P3
// lgkm0, sealed by P3 end-barrier) -> A stages at P4/P1 OK; B-region last
// read P2 -> B stages at P3/P4 OK. LDS 16B-slot XOR swizzle both-sides.
__global__ __launch_bounds__(512, 2) void gemm_8p(
    const unsigned short* __restrict__ A,
    const unsigned short* __restrict__ B,
    const float* __restrict__ bias,
    float* __restrict__ C) {
  __shared__ __align__(16) unsigned short lds[2][2][BM * BK];   // 128 KiB

  const int tid = threadIdx.x;
  const int lane = tid & 63;
  const int wave = tid >> 6;   // 0..7
  const int wr = wave >> 2;    // M half
  const int wc = wave & 3;     // N quarter
  const int l15 = lane & 15;
  const int l4 = lane >> 4;

  const int bm = blockIdx.x >> 4;
  const int bn = blockIdx.x & 15;
  const size_t row0 = (size_t)bm * BM;
  const size_t col0 = (size_t)bn * BN;

  auto stage = [&](int buf, int ab, int r0, const unsigned short* __restrict__ src,
                   size_t grow0, int kt) {
    const int rr = tid >> 3;
    const int sl = (tid & 7) ^ (rr & 7);
    const unsigned short* g = src + (grow0 + r0 + rr) * (size_t)IN_F + kt * BK + sl * 8;
    unsigned short* d = &lds[buf][ab][r0 * BK] + wave * 512;
    __builtin_amdgcn_global_load_lds(
        (const __attribute__((address_space(1))) void*)g,
        (__attribute__((address_space(3))) void*)d, 16, 0, 0);
  };
  auto ldA = [&](int buf, int aq, int m, int kk) -> short8 {
    const int r = wr * 128 + aq * 64 + m * 16 + l15;
    const int slot = (kk * 4 + l4) ^ (l15 & 7);
    return *(const short8*)&lds[buf][0][r * BK + slot * 8];
  };
  auto ldB = [&](int buf, int j, int kk) -> short8 {
    const int r = wc * 64 + j * 16 + l15;
    const int slot = (kk * 4 + l4) ^ (l15 & 7);
    return *(const short8*)&lds[buf][1][r * BK + slot * 8];
  };

  floatx4 acc[8][4] = {};
  short8 a[4][2], b[4][2];

  // ---- prologue: T0 full (A+B), T1 B-half set; vmcnt(4) -> T0 landed ----
  stage(0, 0, 0,   A, row0, 0); stage(0, 0, 64,  A, row0, 0);
  stage(0, 0, 128, A, row0, 0); stage(0, 0, 192, A, row0, 0);
  stage(0, 1, 0,   B, col0, 0); stage(0, 1, 64,  B, col0, 0);
  stage(0, 1, 128, B, col0, 0); stage(0, 1, 192, B, col0, 0);
  stage(1, 1, 0,   B, col0, 1); stage(1, 1, 64,  B, col0, 1);
  stage(1, 1, 128, B, col0, 1); stage(1, 1, 192, B, col0, 1);
  asm volatile("s_waitcnt vmcnt(4)" ::: "memory");
  __builtin_amdgcn_s_barrier();

  for (int kt = 0; kt < NT; ++kt) {
    const int c = kt & 1, o = c ^ 1;

    // ---- P1: read Aq0 + B01 [buf c]; stage A(kt+1) rows 0-127 -> buf o ----
    #pragma unroll
    for (int m = 0; m < 4; ++m) { a[m][0] = ldA(c, 0, m, 0); a[m][1] = ldA(c, 0, m, 1); }
    #pragma unroll
    for (int n = 0; n < 2; ++n) { b[n][0] = ldB(c, n, 0); b[n][1] = ldB(c, n, 1); }
    if (kt + 1 < NT) { stage(o, 0, 0, A, row0, kt + 1); stage(o, 0, 64, A, row0, kt + 1); }
    __builtin_amdgcn_s_barrier();
    asm volatile("s_waitcnt lgkmcnt(0)" ::: "memory");
    __builtin_amdgcn_s_setprio(1);
    #pragma unroll
    for (int m = 0; m < 4; ++m)
      #pragma unroll
      for (int n = 0; n < 2; ++n) {
        MFMA_BF16(acc[m][n], a[m][0], b[n][0]);
        MFMA_BF16(acc[m][n], a[m][1], b[n][1]);
      }
    __builtin_amdgcn_s_setprio(0);
    __builtin_amdgcn_s_barrier();

    // ---- P2: read B23 [buf c]; stage A(kt+1) rows 128-255 -> buf o ----
    #pragma unroll
    for (int n = 2; n < 4; ++n) { b[n][0] = ldB(c, n, 0); b[n][1] = ldB(c, n, 1); }
    if (kt + 1 < NT) { stage(o, 0, 128, A, row0, kt + 1); stage(o, 0, 192, A, row0, kt + 1); }
    __builtin_amdgcn_s_barrier();
    asm volatile("s_waitcnt lgkmcnt(0)" ::: "memory");
    __builtin_amdgcn_s_setprio(1);
    #pragma unroll
    for (int m = 0; m < 4; ++m)
      #pragma unroll
      for (int n = 2; n < 4; ++n) {
        MFMA_BF16(acc[m][n], a[m][0], b[n][0]);
        MFMA_BF16(acc[m][n], a[m][1], b[n][1]);
      }
    __builtin_amdgcn_s_setprio(0);
    __builtin_amdgcn_s_barrier();

    // ---- P3: read Aq1 [buf c]; stage B(kt+2) rows 0-127 -> buf c ----
    #pragma unroll
    for (int m = 0; m < 4; ++m) { a[m][0] = ldA(c, 1, m, 0); a[m][1] = ldA(c, 1, m, 1); }
    if (kt + 2 < NT) { stage(c, 1, 0, B, col0, kt + 2); stage(c, 1, 64, B, col0, kt + 2); }
    __builtin_amdgcn_s_barrier();
    asm volatile("s_waitcnt lgkmcnt(0)" ::: "memory");
    __builtin_amdgcn_s_setprio(1);
    #pragma unroll
    for (int m = 0; m < 4; ++m)
      #pragma unroll
      for (int n = 2; n < 4; ++n) {
        MFMA_BF16(acc[4 + m][n], a[m][0], b[n][0]);
        MFMA_BF16(acc[4 + m][n], a[m][1], b[n][1]);
      }
    __builtin_amdgcn_s_setprio(0);
    __builtin_amdgcn_s_barrier();

    // ---- P4: stage B(kt+2) rows 128-255 -> buf c; MFMA q1 x b01;
    //          vmcnt(4) before end barrier guarantees tile kt+1 landed ----
    if (kt + 2 < NT) { stage(c, 1, 128, B, col0, kt + 2); stage(c, 1, 192, B, col0, kt + 2); }
    __builtin_amdgcn_s_barrier();
    __builtin_amdgcn_s_setprio(1);
    #pragma unroll
    for (int m = 0; m < 4; ++m)
      #pragma unroll
      for (int n = 0; n < 2; ++n) {
        MFMA_BF16(acc[4 + m][n], a[m][0], b[n][0]);   // b01 live since P1
        MFMA_BF16(acc[4 + m][n], a[m][1], b[n][1]);
      }
    __builtin_amdgcn_s_setprio(0);
    if (kt + 2 < NT) {
      asm volatile("s_waitcnt vmcnt(4)" ::: "memory");   // all of kt+1 landed
    } else {
      asm volatile("s_waitcnt vmcnt(0)" ::: "memory");   // tail: drain
    }
    __builtin_amdgcn_s_barrier();
  }

  // ---- epilogue: C = acc + bias.  D layout: row=(lane>>4)*4+r, col=lane&15
  #pragma unroll
  for (int n = 0; n < 4; ++n) {
    const size_t col = col0 + wc * 64 + n * 16 + l15;
    const float bv = bias[col];
    #pragma unroll
    for (int m = 0; m < 8; ++m) {
      const size_t rw = row0 + wr * 128 + m * 16 + l4 * 4;
      #pragma unroll
      for (int r = 0; r < 4; ++r)
        C[(rw + r) * OUT_F + col] = acc[m][n][r] + bv;
    }
  }
}

// ---- safety net: fp32 tiled GEMM w/ on-the-fly weight ----
__global__ void fallback_gemm(const float* __restrict__ x, const float* __restrict__ cp,
                              const float* __restrict__ resid, const float* __restrict__ bias,
                              float* __restrict__ out) {
  __shared__ float xs[64][32];
  __shared__ float ws[64][33];
  const int tid = threadIdx.x;
  const int bm = blockIdx.x / (OUT_F / 64);
  const int bn = blockIdx.x % (OUT_F / 64);
  const int row0 = bm * 64, col0 = bn * 64;
  const int tr = tid >> 4, tc = tid & 15;
  float acc[4][4] = {};
  for (int k0 = 0; k0 < IN_F; k0 += 32) {
    #pragma unroll
    for (int q = 0; q < 8; ++q) {
      int e = q * 256 + tid;
      int r = e >> 5, cc = e & 31;
      xs[r][cc] = x[(size_t)(row0 + r) * IN_F + k0 + cc];
      int o = col0 + r;
      int j; float c0, c1, c2, c3;
      cr_coeffs(o, j, c0, c1, c2, c3);
      size_t ci = (size_t)(j - 1) * IN_F + k0 + cc;
      ws[r][cc] = c0 * cp[ci] + c1 * cp[ci + IN_F] + c2 * cp[ci + 2 * IN_F] +
                  c3 * cp[ci + 3 * IN_F] + resid[(size_t)o * IN_F + k0 + cc];
    }
    __syncthreads();
    #pragma unroll
    for (int kk = 0; kk < 32; ++kk) {
      float xv[4], wv[4];
      #pragma unroll
      for (int i = 0; i < 4; ++i) xv[i] = xs[tr * 4 + i][kk];
      #pragma unroll
      for (int i = 0; i < 4; ++i) wv[i] = ws[tc * 4 + i][kk];
      #pragma unroll
      for (int i = 0; i < 4; ++i)
        #pragma unroll
        for (int jj = 0; jj < 4; ++jj) acc[i][jj] += xv[i] * wv[jj];
    }
    __syncthreads();
  }
  #pragma unroll
  for (int i = 0; i < 4; ++i)
    #pragma unroll
    for (int jj = 0; jj < 4; ++jj) {
      int row = row0 + tr * 4 + i, col = col0 + tc * 4 + jj;
      out[(size_t)row * OUT_F + col] = acc[i][jj] + bias[col];
    }
}

extern "C" void kernel_launch(void* const* d_in, const int* in_sizes, int n_in,
                              void* d_out, int out_size, void* d_ws, size_t ws_size,
                              hipStream_t stream) {
  const float* x = (const float*)d_in[0];
  const float* cp = (const float*)d_in[1];
  const float* resid = (const float*)d_in[2];
  const float* bias = (const float*)d_in[3];
  float* out = (float*)d_out;

  const size_t wb_bytes = (size_t)OUT_F * IN_F * 2;
  const size_t xb_bytes = (size_t)NROWS * IN_F * 2;

  if (ws_size >= wb_bytes + xb_bytes) {
    unsigned short* wb = (unsigned short*)d_ws;
    unsigned short* xb = (unsigned short*)((char*)d_ws + wb_bytes);
    hipLaunchKernelGGL(build_w, dim3(16384), dim3(256), 0, stream, cp, resid, wb);
    hipLaunchKernelGGL(convert_x, dim3(16384), dim3(256), 0, stream, x, xb);
    hipLaunchKernelGGL(gemm_8p, dim3(512), dim3(512), 0, stream, xb, wb, bias, out);
  } else {
    hipLaunchKernelGGL(fallback_gemm, dim3((NROWS / 64) * (OUT_F / 64)), dim3(256), 0,
                       stream, x, cp, resid, bias, out);
  }
}